// Round 6
// baseline (212.957 us; speedup 1.0000x reference)
//
#include <hip/hip_runtime.h>
#include <hip/hip_cooperative_groups.h>
#include <math.h>

#define EMBED 128
#define NSAMP 5
#define BLOCK 256
#define NBLOCKS 1024
#define GROUPS_PER_BLOCK (BLOCK / 32)
#define TOTAL_GROUPS (NBLOCKS * GROUPS_PER_BLOCK)   // 8192 -> 8 rows/group

namespace cg = cooperative_groups;

__device__ __forceinline__ float log_sigmoid(float x) {
    // stable: min(x,0) - log1p(exp(-|x|))
    return fminf(x, 0.0f) - log1pf(__expf(-fabsf(x)));
}

__device__ __forceinline__ float dot4(float4 a, float4 b) {
    return a.x * b.x + a.y * b.y + a.z * b.z + a.w * b.w;
}

// __launch_bounds__(256, 4): 4 waves/EU -> 4 blocks/CU -> 1024 blocks
// guaranteed co-resident on 256 CUs (cooperative-launch requirement).
__global__ __launch_bounds__(BLOCK, 4) void nsloss_coop(
    const float* __restrict__ embs,
    const int* __restrict__ label,
    const int* __restrict__ negs,
    const float* __restrict__ weights,
    float* __restrict__ partials,       // [NBLOCKS] in d_ws
    float* __restrict__ out,
    int n, float inv_n)
{
    const int tid = threadIdx.x;
    const int lane = tid & 31;                 // 32 lanes * float4 = 128 floats/row
    const int group = blockIdx.x * GROUPS_PER_BLOCK + (tid >> 5);

    float acc = 0.0f;

    for (int row = group; row < n; row += TOTAL_GROUPS) {
        const float4 e = *reinterpret_cast<const float4*>(
            embs + (size_t)row * EMBED + lane * 4);

        int idx[6];
        idx[0] = label[row];
        const int* nrow = negs + (size_t)row * NSAMP;
        #pragma unroll
        for (int s = 0; s < NSAMP; ++s) idx[1 + s] = nrow[s];

        float d[6];
        #pragma unroll
        for (int k = 0; k < 6; ++k) {
            const float4 wv = *reinterpret_cast<const float4*>(
                weights + (size_t)idx[k] * EMBED + lane * 4);
            d[k] = dot4(e, wv);
        }

        // butterfly reduce within each 32-lane half (masks <32 stay in-half)
        #pragma unroll
        for (int off = 16; off > 0; off >>= 1) {
            #pragma unroll
            for (int k = 0; k < 6; ++k) d[k] += __shfl_xor(d[k], off);
        }

        if (lane == 0) {
            float row_loss = log_sigmoid(d[0]);        // positive term
            #pragma unroll
            for (int s = 1; s < 6; ++s)
                row_loss += log_sigmoid(-d[s]);        // noise = -w
            acc += row_loss;
        }
    }

    // ---- per-block reduction ----
    __shared__ float sdata[BLOCK];
    sdata[tid] = acc;
    __syncthreads();
    #pragma unroll
    for (int s = BLOCK / 2; s > 0; s >>= 1) {
        if (tid < s) sdata[tid] += sdata[tid + s];
        __syncthreads();
    }
    if (tid == 0) {
        // agent-scope release: partial must be visible across XCDs at grid sync
        __hip_atomic_store(&partials[blockIdx.x], sdata[0],
                           __ATOMIC_RELEASE, __HIP_MEMORY_SCOPE_AGENT);
    }

    cg::this_grid().sync();

    // ---- block 0 finishes: deterministic double-precision tree ----
    if (blockIdx.x == 0) {
        double a = 0.0;
        for (int i = tid; i < NBLOCKS; i += BLOCK)
            a += (double)__hip_atomic_load(&partials[i],
                           __ATOMIC_RELAXED, __HIP_MEMORY_SCOPE_AGENT);
        __shared__ double sd[BLOCK];
        sd[tid] = a;
        __syncthreads();
        #pragma unroll
        for (int s = BLOCK / 2; s > 0; s >>= 1) {
            if (tid < s) sd[tid] += sd[tid + s];
            __syncthreads();
        }
        if (tid == 0)
            out[0] = (float)(-sd[0] * (double)inv_n);
    }
}

extern "C" void kernel_launch(void* const* d_in, const int* in_sizes, int n_in,
                              void* d_out, int out_size, void* d_ws, size_t ws_size,
                              hipStream_t stream) {
    // setup_inputs order: input(int), embs(f32), label(int), negs(int), weights(f32)
    const float* embs    = (const float*)d_in[1];
    const int*   label   = (const int*)d_in[2];
    const int*   negs    = (const int*)d_in[3];
    const float* weights = (const float*)d_in[4];
    int n = in_sizes[0];                        // 65536
    float inv_n = 1.0f / (float)n;

    float* partials = (float*)d_ws;             // NBLOCKS * 4 bytes
    float* outp = (float*)d_out;

    void* args[] = { (void*)&embs, (void*)&label, (void*)&negs, (void*)&weights,
                     (void*)&partials, (void*)&outp, (void*)&n, (void*)&inv_n };

    hipLaunchCooperativeKernel((const void*)nsloss_coop,
                               dim3(NBLOCKS), dim3(BLOCK),
                               args, 0, stream);
}

// Round 7
// 51.210 us; speedup vs baseline: 4.1585x; 4.1585x over previous
//
#include <hip/hip_runtime.h>
#include <math.h>

#define EMBED 128
#define NSAMP 5
#define BLOCK 256
#define NBLOCKS 2048

__device__ __forceinline__ float log_sigmoid(float x) {
    // stable: min(x,0) - log1p(exp(-|x|))
    return fminf(x, 0.0f) - log1pf(__expf(-fabsf(x)));
}

__global__ __launch_bounds__(BLOCK) void nsloss_partial(
    const float* __restrict__ embs,
    const int* __restrict__ label,
    const int* __restrict__ negs,
    const float* __restrict__ weights,
    float* __restrict__ partials,
    int n)
{
    const int tid = threadIdx.x;
    const int lane = tid & 31;                 // 32 lanes * float4 = 128 floats/row
    const int group_in_block = tid >> 5;       // 0..7
    const int groups_per_block = BLOCK >> 5;
    const int group = blockIdx.x * groups_per_block + group_in_block;
    const int total_groups = gridDim.x * groups_per_block;

    float acc = 0.0f;

    for (int row = group; row < n; row += total_groups) {
        const float4 e = *reinterpret_cast<const float4*>(
            embs + (size_t)row * EMBED + lane * 4);

        // 6 gathered rows: label + 5 negs (broadcast index reads, all lanes same addr)
        int idx[6];
        idx[0] = label[row];
        const int* nrow = negs + (size_t)row * NSAMP;
        #pragma unroll
        for (int s = 0; s < NSAMP; ++s) idx[1 + s] = nrow[s];

        float d[6];
        #pragma unroll
        for (int k = 0; k < 6; ++k) {
            const float4 w = *reinterpret_cast<const float4*>(
                weights + (size_t)idx[k] * EMBED + lane * 4);
            d[k] = e.x * w.x + e.y * w.y + e.z * w.z + e.w * w.w;
        }

        // butterfly reduce within each 32-lane half (masks <32 never cross halves)
        #pragma unroll
        for (int off = 16; off > 0; off >>= 1) {
            #pragma unroll
            for (int k = 0; k < 6; ++k) d[k] += __shfl_xor(d[k], off);
        }

        if (lane == 0) {
            float row_loss = log_sigmoid(d[0]);      // positive term
            #pragma unroll
            for (int s = 1; s < 6; ++s)
                row_loss += log_sigmoid(-d[s]);      // noise = -w  ->  logit = -dot
            acc += row_loss;
        }
    }

    __shared__ float sdata[BLOCK];
    sdata[tid] = acc;
    __syncthreads();
    #pragma unroll
    for (int s = BLOCK / 2; s > 0; s >>= 1) {
        if (tid < s) sdata[tid] += sdata[tid + s];
        __syncthreads();
    }
    if (tid == 0) partials[blockIdx.x] = sdata[0];
}

__global__ __launch_bounds__(BLOCK) void nsloss_final(
    const float* __restrict__ partials, int nparts,
    float* __restrict__ out, float inv_n)
{
    double acc = 0.0;
    for (int i = threadIdx.x; i < nparts; i += BLOCK)
        acc += (double)partials[i];

    __shared__ double sd[BLOCK];
    sd[threadIdx.x] = acc;
    __syncthreads();
    #pragma unroll
    for (int s = BLOCK / 2; s > 0; s >>= 1) {
        if (threadIdx.x < s) sd[threadIdx.x] += sd[threadIdx.x + s];
        __syncthreads();
    }
    if (threadIdx.x == 0)
        out[0] = (float)(-sd[0] * (double)inv_n);
}

extern "C" void kernel_launch(void* const* d_in, const int* in_sizes, int n_in,
                              void* d_out, int out_size, void* d_ws, size_t ws_size,
                              hipStream_t stream) {
    // setup_inputs order: input(int), embs(f32), label(int), negs(int), weights(f32)
    const float* embs    = (const float*)d_in[1];
    const int*   label   = (const int*)d_in[2];
    const int*   negs    = (const int*)d_in[3];
    const float* weights = (const float*)d_in[4];
    const int n = in_sizes[0];                  // 65536

    float* partials = (float*)d_ws;             // NBLOCKS * 4 bytes

    nsloss_partial<<<NBLOCKS, BLOCK, 0, stream>>>(embs, label, negs, weights,
                                                  partials, n);
    nsloss_final<<<1, BLOCK, 0, stream>>>(partials, NBLOCKS, (float*)d_out,
                                          1.0f / (float)n);
}